// Round 3
// baseline (53.810 us; speedup 1.0000x reference)
//
#include <hip/hip_runtime.h>

typedef float f32x4 __attribute__((ext_vector_type(4)));

// Problem constants (from reference setup_inputs)
#define B_DIM   4
#define A_DIM   200
#define F_DIM   128
#define OUT_DIM 128
#define NROW    (B_DIM * A_DIM)          // 800
#define HJ_OFF  (NROW * (OUT_DIM / 4))   // f32x4 offset of h_j block

// Kernel A: per-(b,a)-row dual half-GEMM.
// h layout in workspace: [0 .. 800*128)         = h_i + bias
//                        [800*128 .. 2*800*128) = h_j
__global__ void __launch_bounds__(128) gemm_h_kernel(
    const float* __restrict__ x,      // [B*A, F]
    const float* __restrict__ W,      // [2F, OUT]
    const float* __restrict__ bias,   // [OUT]
    float* __restrict__ h)            // [2, B*A, OUT]
{
    const int row = blockIdx.x;       // 0..799  (b*A + a)
    const int o   = threadIdx.x;      // 0..127
    __shared__ float xs[F_DIM];
    xs[o] = x[row * F_DIM + o];
    __syncthreads();

    float acc1 = 0.f, acc2 = 0.f;
#pragma unroll
    for (int f = 0; f < F_DIM; ++f) {
        const float xv = xs[f];                       // LDS broadcast, no conflict
        acc1 = fmaf(xv, W[f * OUT_DIM + o], acc1);            // W[:F] coalesced
        acc2 = fmaf(xv, W[(F_DIM + f) * OUT_DIM + o], acc2);  // W[F:] coalesced
    }
    h[row * OUT_DIM + o]          = acc1 + bias[o];
    h[(NROW + row) * OUT_DIM + o] = acc2;
}

// Kernel B: write-bound broadcast expand.
// One thread per (jrow, o4): jrow = (b*A+i)*A + j in [0,160000), o4 in [0,32).
// Loads hi/hj ONCE, emits all 3 c-rows (they share the same pair vector).
__global__ void __launch_bounds__(256) expand_kernel(
    const f32x4* __restrict__ h4,     // hi4 then hj4
    const float* __restrict__ dist,   // [B*A*A*3]
    f32x4* __restrict__ out)          // [B*A*A*3*(OUT/4)]
{
    const unsigned gid   = blockIdx.x * 256u + threadIdx.x;
    const unsigned o4    = gid & 31u;
    const unsigned jrow  = gid >> 5;            // (b*A+i)*A + j
    const unsigned birow = jrow / 200u;         // b*A + i   (magic-mul)
    const unsigned j     = jrow - birow * 200u;
    const unsigned b     = birow / 200u;        // magic-mul

    const f32x4 hi = h4[birow * 32u + o4];                // L1-resident (512B/row)
    const f32x4 hj = h4[HJ_OFF + (b * 200u + j) * 32u + o4];

    const f32x4 p = hi + hj;

    const float d0 = dist[jrow * 3u + 0u];      // 12B/thread, coalesced
    const float d1 = dist[jrow * 3u + 1u];
    const float d2 = dist[jrow * 3u + 2u];

    const f32x4 r0 = p * d0;
    const f32x4 r1 = p * d1;
    const f32x4 r2 = p * d2;

    f32x4* o0 = out + (jrow * 3u + 0u) * 32u + o4;        // streaming, never re-read
    f32x4* o1 = out + (jrow * 3u + 1u) * 32u + o4;
    f32x4* o2 = out + (jrow * 3u + 2u) * 32u + o4;
    __builtin_nontemporal_store(r0, o0);
    __builtin_nontemporal_store(r1, o1);
    __builtin_nontemporal_store(r2, o2);
}

extern "C" void kernel_launch(void* const* d_in, const int* in_sizes, int n_in,
                              void* d_out, int out_size, void* d_ws, size_t ws_size,
                              hipStream_t stream) {
    const float* x    = (const float*)d_in[0];   // scalar_features [B,A,F]
    const float* dist = (const float*)d_in[1];   // distances [B,A,A,3]
    const float* W    = (const float*)d_in[2];   // weight [2F,OUT]
    const float* bias = (const float*)d_in[3];   // bias [OUT]

    float* h = (float*)d_ws;  // needs 2*800*128*4 = 819,200 B of scratch

    gemm_h_kernel<<<NROW, F_DIM, 0, stream>>>(x, W, bias, h);

    // 160000 jrows * 32 f32x4-cols = 5,120,000 threads = 20,000 blocks of 256
    expand_kernel<<<20000, 256, 0, stream>>>((const f32x4*)h, dist,
                                             (f32x4*)d_out);
}

// Round 4
// 49.181 us; speedup vs baseline: 1.0941x; 1.0941x over previous
//
#include <hip/hip_runtime.h>

typedef float f32x4 __attribute__((ext_vector_type(4)));

// Problem constants (from reference setup_inputs)
#define B_DIM   4
#define A_DIM   200
#define F_DIM   128
#define OUT_DIM 128
#define NROW    (B_DIM * A_DIM)          // 800
#define HJ_OFF  (NROW * (OUT_DIM / 4))   // f32x4 offset of h_j block
#define JR_PER_BLK 8                     // 200 % 8 == 0 -> block never spans birow

// Kernel A: per-(b,a)-row dual half-GEMM.
// h layout in workspace: [0 .. 800*128)         = h_i + bias
//                        [800*128 .. 2*800*128) = h_j
__global__ void __launch_bounds__(128) gemm_h_kernel(
    const float* __restrict__ x,      // [B*A, F]
    const float* __restrict__ W,      // [2F, OUT]
    const float* __restrict__ bias,   // [OUT]
    float* __restrict__ h)            // [2, B*A, OUT]
{
    const int row = blockIdx.x;       // 0..799  (b*A + a)
    const int o   = threadIdx.x;      // 0..127
    __shared__ float xs[F_DIM];
    xs[o] = x[row * F_DIM + o];
    __syncthreads();

    float acc1 = 0.f, acc2 = 0.f;
#pragma unroll
    for (int f = 0; f < F_DIM; ++f) {
        const float xv = xs[f];                       // LDS broadcast, no conflict
        acc1 = fmaf(xv, W[f * OUT_DIM + o], acc1);            // W[:F] coalesced
        acc2 = fmaf(xv, W[(F_DIM + f) * OUT_DIM + o], acc2);  // W[F:] coalesced
    }
    h[row * OUT_DIM + o]          = acc1 + bias[o];
    h[(NROW + row) * OUT_DIM + o] = acc2;
}

// Kernel B: write-bound broadcast expand, LDS-staged.
// Block = 256 threads = 8 consecutive jrows (one birow). Phase 1: one coalesced
// read burst computes pair=hi+hj into LDS. Phase 2: pure contiguous store
// burst (12 KB per block), no global loads interleaved with the write stream.
__global__ void __launch_bounds__(256) expand_kernel(
    const f32x4* __restrict__ h4,     // hi4 then hj4
    const float* __restrict__ dist,   // [B*A*A*3]
    f32x4* __restrict__ out)          // [B*A*A*3*(OUT/4)]
{
    __shared__ f32x4 pairLDS[JR_PER_BLK * 32];   // 4 KB
    __shared__ float distLDS[JR_PER_BLK * 3];    // 96 B

    const unsigned t     = threadIdx.x;
    const unsigned jrow0 = blockIdx.x * JR_PER_BLK;
    const unsigned o4    = t & 31u;
    const unsigned jl    = t >> 5;               // 0..7

    // Phase 1: read burst -> LDS
    const unsigned birow = jrow0 / 200u;         // same for all 8 jrows (200%8==0)
    const unsigned j0    = jrow0 - birow * 200u;
    const unsigned b     = birow / 200u;

    const f32x4 hi = h4[birow * 32u + o4];                       // L1-resident
    const f32x4 hj = h4[HJ_OFF + (b * 200u + j0 + jl) * 32u + o4];
    pairLDS[t] = hi + hj;
    if (t < JR_PER_BLK * 3) distLDS[t] = dist[jrow0 * 3u + t];
    __syncthreads();

    // Phase 2: pure store burst (3 x 16B per thread, 12 KB contiguous per block)
    const f32x4 p  = pairLDS[t];
    const float d0 = distLDS[jl * 3u + 0u];
    const float d1 = distLDS[jl * 3u + 1u];
    const float d2 = distLDS[jl * 3u + 2u];

    f32x4* obase = out + (jrow0 + jl) * 3u * 32u + o4;
    obase[0]  = p * d0;
    obase[32] = p * d1;
    obase[64] = p * d2;
}

extern "C" void kernel_launch(void* const* d_in, const int* in_sizes, int n_in,
                              void* d_out, int out_size, void* d_ws, size_t ws_size,
                              hipStream_t stream) {
    const float* x    = (const float*)d_in[0];   // scalar_features [B,A,F]
    const float* dist = (const float*)d_in[1];   // distances [B,A,A,3]
    const float* W    = (const float*)d_in[2];   // weight [2F,OUT]
    const float* bias = (const float*)d_in[3];   // bias [OUT]

    float* h = (float*)d_ws;  // needs 2*800*128*4 = 819,200 B of scratch

    gemm_h_kernel<<<NROW, F_DIM, 0, stream>>>(x, W, bias, h);

    // 160000 jrows / 8 per block = 20000 blocks of 256 threads
    expand_kernel<<<20000, 256, 0, stream>>>((const f32x4*)h, dist,
                                             (f32x4*)d_out);
}